// Round 22
// baseline (44.533 us; speedup 1.0000x reference)
//
#include <hip/hip_runtime.h>
#include <math.h>

#define NPTS 16384
#define NSMP 8192          // 8 * 1024
#define KNN 10
#define QPB 8              // queries per block
#define WAVES 4            // waves per block
#define HALF 8192          // points per block (half a batch)
#define GPW 16             // 128-pt groups per wave (2048 pts/wave)
#define CAP 48             // candidate buffer capacity per (query, half)
#define LCAP 96            // flagged-substream list capacity

typedef float v2f __attribute__((ext_vector_type(2)));
typedef unsigned long long u64;

// order-preserving float -> uint bijection
__device__ __forceinline__ unsigned mapf(float f) {
    unsigned u = __float_as_uint(f);
    return (u & 0x80000000u) ? ~u : (u | 0x80000000u);
}
__device__ __forceinline__ float unmapf(unsigned k) {
    unsigned u = (k & 0x80000000u) ? (k ^ 0x80000000u) : ~k;
    return __uint_as_float(u);
}
// force a block-uniform value into an SGPR
__device__ __forceinline__ float uniform_f(float x) {
    return __uint_as_float(__builtin_amdgcn_readfirstlane(__float_as_uint(x)));
}

// Two layouts (R17-proven):
//  pk  (plane-paired scan):
//   pk[(b*128+g)*128 + l]      = {x_l, x_{l+64}, y_l, y_{l+64}}
//   pk[(b*128+g)*128 + 64 + l] = {z_l, z_{l+64}, w_l, w_{l+64}}   (w = |p|^2)
//  pk2 (linear, rescan + gather): pk2[b*16384 + idx] = {x, y, z, |p|^2}
__global__ __launch_bounds__(256) void pack_kernel(const float* __restrict__ xyz,
                                                   float4* __restrict__ pk,
                                                   float4* __restrict__ pk2) {
    const int t = blockIdx.x * 256 + threadIdx.x;   // 65536 threads = point pairs
    const int b = t >> 13;          // batch
    const int r = t & 8191;
    const int g = r >> 6;           // group (128 pts)
    const int l = r & 63;           // lane slot
    const float* pA = xyz + ((size_t)b * NPTS + (size_t)g * 128 + l) * 3;
    const float* pB = pA + 64 * 3;
    const float xA = pA[0], yA = pA[1], zA = pA[2];
    const float xB = pB[0], yB = pB[1], zB = pB[2];
    const float wA = fmaf(xA, xA, fmaf(yA, yA, zA * zA));
    const float wB = fmaf(xB, xB, fmaf(yB, yB, zB * zB));
    float4* dst = pk + ((size_t)(b * 128 + g) * 128);
    dst[l]      = make_float4(xA, xB, yA, yB);
    dst[l + 64] = make_float4(zA, zB, wA, wB);
    float4* dst2 = pk2 + (size_t)b * NPTS + (size_t)g * 128;
    dst2[l]      = make_float4(xA, yA, zA, wA);
    dst2[l + 64] = make_float4(xB, yB, zB, wB);
}

// Lean partial kNN at 8 waves/SIMD: 2048 blocks x 256 threads, block = (qg, h).
// Wave scans 2048 pts; wave w owns queries {w, w+4}: tau -> flag -> targeted
// rescan -> canonical rank -> sorted half-top-10 keys to ws2.
__global__ __launch_bounds__(256) void knn_kernel(
    const float4* __restrict__ pk,
    const float4* __restrict__ pk2,
    const float* __restrict__ sxyz,
    u64* __restrict__ ws2)
{
    __shared__ float minBuf[QPB][512];          // 16 KB: 512 substream minima / query
    __shared__ int   cnt[QPB];
    __shared__ int   list[WAVES][LCAP];         // 1.5 KB (reused per tail)
    __shared__ u64   candK[QPB][CAP];           // 3 KB
    __shared__ u64   sort10[QPB][KNN];

    const int lane  = threadIdx.x & 63;
    const int w     = threadIdx.x >> 6;         // wave id = point split id (0..3)
    const int h     = blockIdx.x & 1;           // point half
    const int qg    = blockIdx.x >> 1;
    const int qbase = qg * QPB;
    const int b     = qbase >> 10;              // batch

    if (threadIdx.x < QPB) cnt[threadIdx.x] = 0;

    // all 8 query constants, premultiplied by -2, pinned to SGPRs
    float ax[QPB], ay[QPB], az[QPB];
    #pragma unroll
    for (int q = 0; q < QPB; ++q) {
        const float* s = sxyz + (size_t)(qbase + q) * 3;
        ax[q] = uniform_f(-2.f * s[0]);
        ay[q] = uniform_f(-2.f * s[1]);
        az[q] = uniform_f(-2.f * s[2]);
    }

    // this wave's 16 groups: global group = h*64 + w*16
    const float4* pw = pk + ((size_t)(b * 128 + h * 64 + w * 16)) * 128 + lane;

    // ------- pass A (the ONLY full scan): 2-group batches, 4 loads in flight -------
    v2f mn[QPB];
    #pragma unroll
    for (int q = 0; q < QPB; ++q) { mn[q].x = INFINITY; mn[q].y = INFINITY; }

    #pragma unroll 1
    for (int j = 0; j < GPW; j += 2) {
        const float4 a0 = pw[(size_t)(j + 0) * 128], a1 = pw[(size_t)(j + 0) * 128 + 64];
        const float4 b0 = pw[(size_t)(j + 1) * 128], b1 = pw[(size_t)(j + 1) * 128 + 64];
        {
            const v2f X = {a0.x, a0.y}, Y = {a0.z, a0.w}, Z = {a1.x, a1.y}, W = {a1.z, a1.w};
            #pragma unroll
            for (int q = 0; q < QPB; ++q) {
                const v2f d = X * ax[q] + (Y * ay[q] + (Z * az[q] + W));
                mn[q] = __builtin_elementwise_min(mn[q], d);
            }
        }
        {
            const v2f X = {b0.x, b0.y}, Y = {b0.z, b0.w}, Z = {b1.x, b1.y}, W = {b1.z, b1.w};
            #pragma unroll
            for (int q = 0; q < QPB; ++q) {
                const v2f d = X * ax[q] + (Y * ay[q] + (Z * az[q] + W));
                mn[q] = __builtin_elementwise_min(mn[q], d);
            }
        }
    }
    // substream s = w*128 + hh*64 + lane covers 16 pts: idx = (h*64+w*16+j)*128 + hh*64 + lane
    #pragma unroll
    for (int q = 0; q < QPB; ++q) {
        minBuf[q][w * 128 + lane]      = mn[q].x;
        minBuf[q][w * 128 + 64 + lane] = mn[q].y;
    }
    __syncthreads();                            // the only block barrier

    // ======= tails: wave w owns queries {w, w+4}; all phases wave-local =======
    const float4* p2 = pk2 + (size_t)b * NPTS;

    #pragma unroll 1
    for (int qi = 0; qi < 2; ++qi) {
        const int rq  = w + qi * WAVES;
        const int gid = qbase + rq;
        const float* sq = sxyz + (size_t)gid * 3;
        const float bx = -2.f * sq[0], by = -2.f * sq[1], bz = -2.f * sq[2];

        // this lane's 8 substream minima
        float mh[8];
        #pragma unroll
        for (int s8 = 0; s8 < 8; ++s8)
            mh[s8] = minBuf[rq][(s8 >> 1) * 128 + (s8 & 1) * 64 + lane];

        // tau: binary search over 64 folded minima (disjoint 128-pt partitions).
        // count(folded min <= tau) >= 10 => >=10 distinct pts <= tau => tau >= d10(half).
        float vm = mh[0];
        #pragma unroll
        for (int s8 = 1; s8 < 8; ++s8) vm = fminf(vm, mh[s8]);
        const unsigned um = mapf(vm);
        unsigned lo = 0u, hi = 0xFFFFFFFFu;
        #pragma unroll 1
        for (int it = 0; it < 16; ++it) {
            const unsigned mid = lo + ((hi - lo) >> 1);
            const int c = __popcll(__ballot(um <= mid));
            if (c >= KNN) hi = mid; else lo = mid + 1;
        }
        const float tau = unmapf(hi);

        // flag + compact substreams with min <= tau (covers every pt <= tau)
        int nf = 0;
        #pragma unroll
        for (int s8 = 0; s8 < 8; ++s8) {
            const bool flg = (mh[s8] <= tau);
            const u64 m = __ballot(flg);
            const int pos = nf + __popcll(m & ((1ull << lane) - 1ull));
            if (flg && pos < LCAP) list[w][pos] = (s8 >> 1) * 128 + (s8 & 1) * 64 + lane;
            nf += __popcll(m);
        }
        if (nf > LCAP) nf = LCAP;

        // targeted rescan: nf*16 points (~200), aligned float4 from pk2
        const int total = nf * 16;
        for (int i = lane; i < total; i += 64) {
            const int sid = list[w][i >> 4];
            const int p   = i & 15;
            const int idx = ((h * 64 + ((sid >> 7) << 4) + p) << 7) + (sid & 127);
            const float4 pt = p2[idx];
            const float d = fmaf(pt.x, bx, fmaf(pt.y, by, fmaf(pt.z, bz, pt.w)));
            if (d <= tau) {
                const int sl = atomicAdd(&cnt[rq], 1);
                if (sl < CAP) candK[rq][sl] = ((u64)mapf(d) << 32) | (unsigned)idx;
            }
        }

        // canonical rank over c candidates (keys unique via idx low bits)
        const int c = min(cnt[rq], CAP);        // c >= 10 guaranteed
        const u64 k0 = (lane < c) ? candK[rq][lane] : ~0ull;
        int r0 = 0;
        for (int jj = 0; jj < c; ++jj) {
            const u64 kj = candK[rq][jj];       // LDS broadcast read
            r0 += (kj < k0) ? 1 : 0;
        }
        if (lane < c && r0 < KNN) sort10[rq][r0] = k0;
        // wave-local LDS RAW (lockstep wave64): compiler inserts lgkmcnt wait
        if (lane < KNN) ws2[(size_t)gid * (2 * KNN) + h * KNN + lane] = sort10[rq][lane];
    }
}

// Final merge (R12/R13-proven): one wave per query. Re-rank 20 sorted partial
// keys, softmax over the global top-10, weighted coordinate sum, output.
__global__ __launch_bounds__(256) void merge_kernel(
    const u64* __restrict__ ws2,
    const float* __restrict__ xyz,
    const float* __restrict__ sxyz,
    const float* __restrict__ temp,
    float* __restrict__ out)
{
    const int lane = threadIdx.x & 63;
    const int gid  = blockIdx.x * 4 + (threadIdx.x >> 6);
    const int b    = gid >> 10;

    const u64 k = (lane < 2 * KNN) ? ws2[(size_t)gid * (2 * KNN) + lane] : ~0ull;
    int r = 0;
    #pragma unroll
    for (int jj = 0; jj < 2 * KNN; ++jj) {
        const u64 kj = __shfl(k, jj);
        r += (kj < k) ? 1 : 0;
    }
    // rank-0 key (global min) for the softmax shift
    const unsigned long long mm = __ballot(r == 0 && lane < 2 * KNN);
    const u64 kmin = __shfl(k, (int)__builtin_ctzll(mm));

    const float* s = sxyz + (size_t)gid * 3;
    const float q2 = fmaf(s[0], s[0], fmaf(s[1], s[1], s[2] * s[2]));
    const float t = temp[0];
    const float invt2 = 1.0f / (t * t);
    const float dmin = fmaxf(unmapf((unsigned)(kmin >> 32)) + q2, 0.f);

    const bool sel = (lane < 2 * KNN) && (r < KNN);
    float wgt = 0.f, px = 0.f, py = 0.f, pz = 0.f;
    if (sel) {
        const float d2v = fmaxf(unmapf((unsigned)(k >> 32)) + q2, 0.f);
        wgt = __expf((dmin - d2v) * invt2);
        const int idx = (int)(unsigned)(k & 0xFFFFFFFFull);
        const float* pp = xyz + ((size_t)b * NPTS + idx) * 3;
        px = pp[0]; py = pp[1]; pz = pp[2];
    }
    float sw = wgt, sx = wgt * px, sy = wgt * py, sz = wgt * pz;
    #pragma unroll
    for (int off = 16; off >= 1; off >>= 1) {   // keys live in lanes 0..19
        sw += __shfl_xor(sw, off);
        sx += __shfl_xor(sx, off);
        sy += __shfl_xor(sy, off);
        sz += __shfl_xor(sz, off);
    }
    if (lane == 0) {
        const float inv = 1.0f / sw;
        out[(size_t)gid * 3 + 0] = sx * inv;
        out[(size_t)gid * 3 + 1] = sy * inv;
        out[(size_t)gid * 3 + 2] = sz * inv;
        if (gid == 0) out[NSMP * 3] = t;        // tuple output 2: temp
    }
}

extern "C" void kernel_launch(void* const* d_in, const int* in_sizes, int n_in,
                              void* d_out, int out_size, void* d_ws, size_t ws_size,
                              hipStream_t stream) {
    const float* xyz  = (const float*)d_in[0];   // [8,16384,3]
    const float* sxyz = (const float*)d_in[1];   // [8,1024,3]
    const float* temp = (const float*)d_in[2];   // scalar
    float* out = (float*)d_out;

    float4* pk  = (float4*)d_ws;                               // 2 MiB plane-paired
    float4* pk2 = (float4*)((char*)d_ws + (size_t)131072 * 16); // 2 MiB linear
    u64*    ws2 = (u64*)((char*)d_ws + (size_t)262144 * 16);    // 1.25 MiB partials

    hipLaunchKernelGGL(pack_kernel, dim3(256), dim3(256), 0, stream, xyz, pk, pk2);
    hipLaunchKernelGGL(knn_kernel, dim3(NSMP / QPB * 2), dim3(256), 0, stream,
                       pk, pk2, sxyz, ws2);
    hipLaunchKernelGGL(merge_kernel, dim3(NSMP / 4), dim3(256), 0, stream,
                       ws2, xyz, sxyz, temp, out);
}

// Round 23
// 43.239 us; speedup vs baseline: 1.0299x; 1.0299x over previous
//
#include <hip/hip_runtime.h>
#include <math.h>

#define NPTS 16384
#define NSMP 8192          // 8 * 1024
#define KNN 10
#define QPB 4              // queries per block (shared by all waves)
#define WAVES 4            // waves per block = point-range splits
#define SLICE 4096         // points per wave
#define GPW 32             // 128-pt groups per wave
#define CAP 64             // candidate buffer capacity per query (E[c]~15-25)
#define LCAP 128           // flagged-substream list capacity (per wave)

typedef float v2f __attribute__((ext_vector_type(2)));
typedef unsigned long long u64;

// order-preserving float -> uint bijection
__device__ __forceinline__ unsigned mapf(float f) {
    unsigned u = __float_as_uint(f);
    return (u & 0x80000000u) ? ~u : (u | 0x80000000u);
}
__device__ __forceinline__ float unmapf(unsigned k) {
    unsigned u = (k & 0x80000000u) ? (k ^ 0x80000000u) : ~k;
    return __uint_as_float(u);
}
// force a block-uniform value into an SGPR (frees VGPRs for the hot loop)
__device__ __forceinline__ float uniform_f(float x) {
    return __uint_as_float(__builtin_amdgcn_readfirstlane(__float_as_uint(x)));
}

// Two layouts (R17-proven):
//  pk  (plane-paired, scan):
//   pk[(b*128+g)*128 + l]      = {x_l, x_{l+64}, y_l, y_{l+64}}
//   pk[(b*128+g)*128 + 64 + l] = {z_l, z_{l+64}, w_l, w_{l+64}}   (w = |p|^2)
//  pk2 (linear, rescan + gather): pk2[b*16384 + idx] = {x, y, z, |p|^2}
__global__ __launch_bounds__(256) void pack_kernel(const float* __restrict__ xyz,
                                                   float4* __restrict__ pk,
                                                   float4* __restrict__ pk2) {
    const int t = blockIdx.x * 256 + threadIdx.x;   // 65536 threads = point pairs
    const int b = t >> 13;          // batch
    const int r = t & 8191;
    const int g = r >> 6;           // group (128 pts)
    const int l = r & 63;           // lane slot
    const float* pA = xyz + ((size_t)b * NPTS + (size_t)g * 128 + l) * 3;
    const float* pB = pA + 64 * 3;
    const float xA = pA[0], yA = pA[1], zA = pA[2];
    const float xB = pB[0], yB = pB[1], zB = pB[2];
    const float wA = fmaf(xA, xA, fmaf(yA, yA, zA * zA));
    const float wB = fmaf(xB, xB, fmaf(yB, yB, zB * zB));
    float4* dst = pk + ((size_t)(b * 128 + g) * 128);
    dst[l]      = make_float4(xA, xB, yA, yB);
    dst[l + 64] = make_float4(zA, zB, wA, wB);
    float4* dst2 = pk2 + (size_t)b * NPTS + (size_t)g * 128;
    dst2[l]      = make_float4(xA, yA, zA, wA);
    dst2[l + 64] = make_float4(xB, yB, zB, wB);
}

// Lean single-scan kNN at 8 waves/SIMD: 2048 blocks x 256 threads (R4's
// proven high-issue config), QPB=4, wave w owns exactly query w.
// Substream s in [0,512): s = w*128 + hh*64 + l covers 32 points
//   idx = ((s>>7)*32 + p)*128 + (s & 127),  p in [0,32).
__global__ __launch_bounds__(256) void knn_kernel(
    const float4* __restrict__ pk,
    const float4* __restrict__ pk2,
    const float* __restrict__ sxyz,
    const float* __restrict__ temp,
    float* __restrict__ out)
{
    __shared__ float minBuf[QPB][512];          // 8 KB: 512 substream minima / query
    __shared__ int   cnt[QPB];
    __shared__ int   list[WAVES][LCAP];         // 2 KB: flagged substream ids
    __shared__ u64   candK[QPB][CAP];           // 2 KB
    __shared__ u64   sort10[QPB][KNN];

    const int lane  = threadIdx.x & 63;
    const int w     = threadIdx.x >> 6;         // wave id = point split id (0..3)
    const int qbase = blockIdx.x * QPB;
    const int b     = qbase >> 10;              // batch (256 blocks/batch, no straddle)

    if (threadIdx.x < QPB) cnt[threadIdx.x] = 0;

    // 4 query constants, premultiplied by -2, pinned to SGPRs (block-uniform)
    float ax[QPB], ay[QPB], az[QPB];
    #pragma unroll
    for (int q = 0; q < QPB; ++q) {
        const float* s = sxyz + (size_t)(qbase + q) * 3;
        ax[q] = uniform_f(-2.f * s[0]);
        ay[q] = uniform_f(-2.f * s[1]);
        az[q] = uniform_f(-2.f * s[2]);
    }

    // this wave's 32 groups of the batch's 128
    const float4* pw = pk + ((size_t)(b * 128 + w * 32)) * 128 + lane;

    // ------- pass A (the ONLY full scan): 2-group batches, 4 loads in flight -------
    v2f mn[QPB];
    #pragma unroll
    for (int q = 0; q < QPB; ++q) { mn[q].x = INFINITY; mn[q].y = INFINITY; }

    #pragma unroll 1
    for (int j = 0; j < GPW; j += 2) {
        const float4 a0 = pw[(size_t)(j + 0) * 128], a1 = pw[(size_t)(j + 0) * 128 + 64];
        const float4 b0 = pw[(size_t)(j + 1) * 128], b1 = pw[(size_t)(j + 1) * 128 + 64];
        {
            const v2f X = {a0.x, a0.y}, Y = {a0.z, a0.w}, Z = {a1.x, a1.y}, W = {a1.z, a1.w};
            #pragma unroll
            for (int q = 0; q < QPB; ++q) {
                const v2f d = X * ax[q] + (Y * ay[q] + (Z * az[q] + W));
                mn[q] = __builtin_elementwise_min(mn[q], d);
            }
        }
        {
            const v2f X = {b0.x, b0.y}, Y = {b0.z, b0.w}, Z = {b1.x, b1.y}, W = {b1.z, b1.w};
            #pragma unroll
            for (int q = 0; q < QPB; ++q) {
                const v2f d = X * ax[q] + (Y * ay[q] + (Z * az[q] + W));
                mn[q] = __builtin_elementwise_min(mn[q], d);
            }
        }
    }
    // substream minima: .x -> half 0 (lane), .y -> half 1 (lane+64)
    #pragma unroll
    for (int q = 0; q < QPB; ++q) {
        minBuf[q][w * 128 + lane]      = mn[q].x;
        minBuf[q][w * 128 + 64 + lane] = mn[q].y;
    }
    __syncthreads();                            // the only block barrier

    // ======= tail: wave w owns query w; everything below is wave-local =======
    const float4* p2 = pk2 + (size_t)b * NPTS;
    const int gid = qbase + w;
    const float* sq = sxyz + (size_t)gid * 3;
    const float bx = -2.f * sq[0], by = -2.f * sq[1], bz = -2.f * sq[2];

    // this lane's 8 substream minima (one per (k,hh))
    float mh[8];
    #pragma unroll
    for (int s8 = 0; s8 < 8; ++s8)
        mh[s8] = minBuf[w][(s8 >> 1) * 128 + (s8 & 1) * 64 + lane];

    // tau: binary search over the 64 folded minima (each covers 256 pts).
    // count(folded min <= tau) >= 10 => tau >= 10th substream min >= d10.
    float vm = mh[0];
    #pragma unroll
    for (int s8 = 1; s8 < 8; ++s8) vm = fminf(vm, mh[s8]);
    const unsigned um = mapf(vm);
    unsigned lo = 0u, hi = 0xFFFFFFFFu;
    #pragma unroll 1
    for (int it = 0; it < 16; ++it) {
        const unsigned mid = lo + ((hi - lo) >> 1);
        const int c = __popcll(__ballot(um <= mid));
        if (c >= KNN) hi = mid; else lo = mid + 1;
    }
    const float tau = unmapf(hi);

    // flag + compact substreams with min <= tau (covers every pt <= tau)
    int nf = 0;
    #pragma unroll
    for (int s8 = 0; s8 < 8; ++s8) {
        const bool flg = (mh[s8] <= tau);
        const u64 m = __ballot(flg);
        const int pos = nf + __popcll(m & ((1ull << lane) - 1ull));
        if (flg && pos < LCAP) list[w][pos] = (s8 >> 1) * 128 + (s8 & 1) * 64 + lane;
        nf += __popcll(m);
    }
    if (nf > LCAP) nf = LCAP;

    // targeted rescan: nf*32 points (~400), aligned float4 from pk2
    const int total = nf * 32;
    for (int i = lane; i < total; i += 64) {
        const int s   = list[w][i >> 5];
        const int idx = ((s >> 7) << 12) + ((i & 31) << 7) + (s & 127);
        const float4 pt = p2[idx];
        const float d = fmaf(pt.x, bx, fmaf(pt.y, by, fmaf(pt.z, bz, pt.w)));
        if (d <= tau) {
            const int sl = atomicAdd(&cnt[w], 1);
            if (sl < CAP) candK[w][sl] = ((u64)mapf(d) << 32) | (unsigned)idx;
        }
    }

    // canonical rank over c candidates (keys unique via idx low bits)
    {
        const int c = min(cnt[w], CAP);         // c >= 10 guaranteed (all pts <= tau)
        const u64 k0 = (lane < c) ? candK[w][lane] : ~0ull;
        int r0 = 0;
        for (int jj = 0; jj < c; ++jj) {
            const u64 kj = candK[w][jj];        // LDS broadcast read
            r0 += (kj < k0) ? 1 : 0;
        }
        if (lane < c && r0 < KNN) sort10[w][r0] = k0;
        // wave-local LDS RAW (lockstep wave64): compiler inserts lgkmcnt wait
        const u64 sel = (lane < KNN) ? sort10[w][lane] : ~0ull;

        // epilogue: d2 = max(d' + |q|^2, 0), softmax over 10, weighted coord sum
        const float q2 = fmaf(sq[0], sq[0], fmaf(sq[1], sq[1], sq[2] * sq[2]));
        const float dp = unmapf((unsigned)(sel >> 32));
        const float d2v = fmaxf(dp + q2, 0.f);
        const float dmin = __shfl(d2v, 0);      // lane 0 = rank 0 = smallest
        const float t = temp[0];
        const float invt2 = 1.0f / (t * t);
        float wgt = 0.f, px = 0.f, py = 0.f, pz = 0.f;
        if (lane < KNN) {
            wgt = __expf((dmin - d2v) * invt2);
            const int idx = (int)(unsigned)(sel & 0xFFFFFFFFull);
            const float4 pp = p2[idx];
            px = pp.x; py = pp.y; pz = pp.z;
        }
        float sw = wgt, sx = wgt * px, sy = wgt * py, sz = wgt * pz;
        #pragma unroll
        for (int off = 8; off >= 1; off >>= 1) {
            sw += __shfl_xor(sw, off);
            sx += __shfl_xor(sx, off);
            sy += __shfl_xor(sy, off);
            sz += __shfl_xor(sz, off);
        }
        if (lane == 0) {
            const float inv = 1.0f / sw;
            out[(size_t)gid * 3 + 0] = sx * inv;
            out[(size_t)gid * 3 + 1] = sy * inv;
            out[(size_t)gid * 3 + 2] = sz * inv;
            if (gid == 0) out[NSMP * 3] = t;    // tuple output 2: temp
        }
    }
}

extern "C" void kernel_launch(void* const* d_in, const int* in_sizes, int n_in,
                              void* d_out, int out_size, void* d_ws, size_t ws_size,
                              hipStream_t stream) {
    const float* xyz  = (const float*)d_in[0];   // [8,16384,3]
    const float* sxyz = (const float*)d_in[1];   // [8,1024,3]
    const float* temp = (const float*)d_in[2];   // scalar
    float* out = (float*)d_out;

    float4* pk  = (float4*)d_ws;                              // 2 MiB plane-paired
    float4* pk2 = (float4*)((char*)d_ws + (size_t)131072*16); // 2 MiB linear

    hipLaunchKernelGGL(pack_kernel, dim3(256), dim3(256), 0, stream, xyz, pk, pk2);
    hipLaunchKernelGGL(knn_kernel, dim3(NSMP / QPB), dim3(256), 0, stream,
                       pk, pk2, sxyz, temp, out);
}

// Round 24
// 39.955 us; speedup vs baseline: 1.1146x; 1.0822x over previous
//
#include <hip/hip_runtime.h>
#include <math.h>

#define NPTS 16384
#define NSMP 8192          // 8 * 1024
#define KNN 10
#define QPB 8              // queries per block (shared by all waves)
#define WAVES 4            // waves per block = point-range splits
#define SLICE 4096         // points per wave
#define GPW 32             // 128-pt groups per wave
#define CAP 64             // candidate buffer capacity per query (E[c]~15-25)
#define LCAP 128           // flagged-substream list capacity (per wave, reused)

typedef float v2f __attribute__((ext_vector_type(2)));
typedef unsigned long long u64;

// order-preserving float -> uint bijection
__device__ __forceinline__ unsigned mapf(float f) {
    unsigned u = __float_as_uint(f);
    return (u & 0x80000000u) ? ~u : (u | 0x80000000u);
}
__device__ __forceinline__ float unmapf(unsigned k) {
    unsigned u = (k & 0x80000000u) ? (k ^ 0x80000000u) : ~k;
    return __uint_as_float(u);
}
// force a block-uniform value into an SGPR (frees VGPRs for the hot loop)
__device__ __forceinline__ float uniform_f(float x) {
    return __uint_as_float(__builtin_amdgcn_readfirstlane(__float_as_uint(x)));
}

// Two layouts (R17-proven):
//  pk  (plane-paired, scan):
//   pk[(b*128+g)*128 + l]      = {x_l, x_{l+64}, y_l, y_{l+64}}
//   pk[(b*128+g)*128 + 64 + l] = {z_l, z_{l+64}, w_l, w_{l+64}}   (w = |p|^2)
//  pk2 (linear, rescan + gather): pk2[b*16384 + idx] = {x, y, z, |p|^2}
__global__ __launch_bounds__(256) void pack_kernel(const float* __restrict__ xyz,
                                                   float4* __restrict__ pk,
                                                   float4* __restrict__ pk2) {
    const int t = blockIdx.x * 256 + threadIdx.x;   // 65536 threads = point pairs
    const int b = t >> 13;          // batch
    const int r = t & 8191;
    const int g = r >> 6;           // group (128 pts)
    const int l = r & 63;           // lane slot
    const float* pA = xyz + ((size_t)b * NPTS + (size_t)g * 128 + l) * 3;
    const float* pB = pA + 64 * 3;
    const float xA = pA[0], yA = pA[1], zA = pA[2];
    const float xB = pB[0], yB = pB[1], zB = pB[2];
    const float wA = fmaf(xA, xA, fmaf(yA, yA, zA * zA));
    const float wB = fmaf(xB, xB, fmaf(yB, yB, zB * zB));
    float4* dst = pk + ((size_t)(b * 128 + g) * 128);
    dst[l]      = make_float4(xA, xB, yA, yB);
    dst[l + 64] = make_float4(zA, zB, wA, wB);
    float4* dst2 = pk2 + (size_t)b * NPTS + (size_t)g * 128;
    dst2[l]      = make_float4(xA, yA, zA, wA);
    dst2[l + 64] = make_float4(xB, yB, zB, wB);
}

// Single-scan kNN + targeted rescan in the high-issue shape:
// 1024 blocks x 256 threads (4 waves), QPB=8, wave w owns queries {w, w+4}.
// Substream s in [0,512): s = k*128 + h*64 + l covers 32 points
//   idx = k*4096 + j*128 + (s & 127),  j in [0,32).
__global__ __launch_bounds__(256) void knn_kernel(
    const float4* __restrict__ pk,
    const float4* __restrict__ pk2,
    const float* __restrict__ sxyz,
    const float* __restrict__ temp,
    float* __restrict__ out)
{
    __shared__ float minBuf[QPB][512];          // 16 KB: 512 substream minima / query
    __shared__ int   cnt[QPB];
    __shared__ int   list[WAVES][LCAP];         // 2 KB: flagged substream ids (reused per tail)
    __shared__ u64   candK[QPB][CAP];           // 4 KB
    __shared__ u64   sort10[QPB][KNN];

    const int lane  = threadIdx.x & 63;
    const int w     = threadIdx.x >> 6;         // wave id = point split id (0..3)
    const int qbase = blockIdx.x * QPB;
    const int b     = qbase >> 10;              // batch (128 blocks/batch, no straddle)

    if (threadIdx.x < QPB) cnt[threadIdx.x] = 0;

    // all 8 query constants, premultiplied by -2, pinned to SGPRs (block-uniform)
    float ax[QPB], ay[QPB], az[QPB];
    #pragma unroll
    for (int q = 0; q < QPB; ++q) {
        const float* s = sxyz + (size_t)(qbase + q) * 3;
        ax[q] = uniform_f(-2.f * s[0]);
        ay[q] = uniform_f(-2.f * s[1]);
        az[q] = uniform_f(-2.f * s[2]);
    }

    // this wave's 32 groups of the batch's 128
    const float4* pw = pk + ((size_t)(b * 128 + w * 32)) * 128 + lane;

    // ------- pass A (the ONLY full scan): 2-group batches, 4 loads in flight -------
    v2f mn[QPB];
    #pragma unroll
    for (int q = 0; q < QPB; ++q) { mn[q].x = INFINITY; mn[q].y = INFINITY; }

    #pragma unroll 1
    for (int j = 0; j < GPW; j += 2) {
        const float4 a0 = pw[(size_t)(j + 0) * 128], a1 = pw[(size_t)(j + 0) * 128 + 64];
        const float4 b0 = pw[(size_t)(j + 1) * 128], b1 = pw[(size_t)(j + 1) * 128 + 64];
        {
            const v2f X = {a0.x, a0.y}, Y = {a0.z, a0.w}, Z = {a1.x, a1.y}, W = {a1.z, a1.w};
            #pragma unroll
            for (int q = 0; q < QPB; ++q) {
                const v2f d = X * ax[q] + (Y * ay[q] + (Z * az[q] + W));
                mn[q] = __builtin_elementwise_min(mn[q], d);
            }
        }
        {
            const v2f X = {b0.x, b0.y}, Y = {b0.z, b0.w}, Z = {b1.x, b1.y}, W = {b1.z, b1.w};
            #pragma unroll
            for (int q = 0; q < QPB; ++q) {
                const v2f d = X * ax[q] + (Y * ay[q] + (Z * az[q] + W));
                mn[q] = __builtin_elementwise_min(mn[q], d);
            }
        }
    }
    // substream minima: .x -> half 0 (lane), .y -> half 1 (lane+64)
    #pragma unroll
    for (int q = 0; q < QPB; ++q) {
        minBuf[q][w * 128 + lane]      = mn[q].x;
        minBuf[q][w * 128 + 64 + lane] = mn[q].y;
    }
    __syncthreads();                            // the only block barrier

    // ======= tails: wave w owns queries {w, w+4}; all phases wave-local =======
    const float4* p2 = pk2 + (size_t)b * NPTS;
    const float t = temp[0];
    const float invt2 = 1.0f / (t * t);

    #pragma unroll 1
    for (int qi = 0; qi < 2; ++qi) {
        const int rq  = w + qi * WAVES;
        const int gid = qbase + rq;
        const float* sq = sxyz + (size_t)gid * 3;
        const float bx = -2.f * sq[0], by = -2.f * sq[1], bz = -2.f * sq[2];

        // load this lane's 8 substream minima (one per (k,h))
        float mh[8];
        #pragma unroll
        for (int s8 = 0; s8 < 8; ++s8)
            mh[s8] = minBuf[rq][(s8 >> 1) * 128 + (s8 & 1) * 64 + lane];

        // tau: binary search over the 64 folded minima (each covers 256 pts).
        // count(folded min <= tau) >= 10 => tau >= 10th substream min >= d10.
        float vm = mh[0];
        #pragma unroll
        for (int s8 = 1; s8 < 8; ++s8) vm = fminf(vm, mh[s8]);
        const unsigned um = mapf(vm);
        unsigned lo = 0u, hi = 0xFFFFFFFFu;
        #pragma unroll 1
        for (int it = 0; it < 16; ++it) {
            const unsigned mid = lo + ((hi - lo) >> 1);
            const int c = __popcll(__ballot(um <= mid));
            if (c >= KNN) hi = mid; else lo = mid + 1;
        }
        const float tau = unmapf(hi);

        // flag + compact substreams with min <= tau (covers every pt <= tau)
        int nf = 0;
        #pragma unroll
        for (int s8 = 0; s8 < 8; ++s8) {
            const bool flg = (mh[s8] <= tau);
            const u64 m = __ballot(flg);
            const int pos = nf + __popcll(m & ((1ull << lane) - 1ull));
            if (flg && pos < LCAP) list[w][pos] = (s8 >> 1) * 128 + (s8 & 1) * 64 + lane;
            nf += __popcll(m);
        }
        if (nf > LCAP) nf = LCAP;

        // targeted rescan: nf*32 points (~400), aligned float4 from pk2
        const int total = nf * 32;
        for (int i = lane; i < total; i += 64) {
            const int s   = list[w][i >> 5];
            const int idx = ((s >> 7) << 12) + ((i & 31) << 7) + (s & 127);
            const float4 pt = p2[idx];
            const float d = fmaf(pt.x, bx, fmaf(pt.y, by, fmaf(pt.z, bz, pt.w)));
            if (d <= tau) {
                const int sl = atomicAdd(&cnt[rq], 1);
                if (sl < CAP) candK[rq][sl] = ((u64)mapf(d) << 32) | (unsigned)idx;
            }
        }

        // canonical rank over c candidates (keys unique via idx low bits)
        const int c = min(cnt[rq], CAP);        // c >= 10 guaranteed (all pts <= tau)
        const u64 k0 = (lane < c) ? candK[rq][lane] : ~0ull;
        int r0 = 0;
        for (int jj = 0; jj < c; ++jj) {
            const u64 kj = candK[rq][jj];       // LDS broadcast read
            r0 += (kj < k0) ? 1 : 0;
        }
        if (lane < c && r0 < KNN) sort10[rq][r0] = k0;
        // wave-local LDS RAW (lockstep wave64): compiler inserts lgkmcnt wait
        const u64 sel = (lane < KNN) ? sort10[rq][lane] : ~0ull;

        // epilogue: d2 = max(d' + |q|^2, 0), softmax over 10, weighted coord sum
        const float q2 = fmaf(sq[0], sq[0], fmaf(sq[1], sq[1], sq[2] * sq[2]));
        const float dp = unmapf((unsigned)(sel >> 32));
        const float d2v = fmaxf(dp + q2, 0.f);
        const float dmin = __shfl(d2v, 0);      // lane 0 = rank 0 = smallest
        float wgt = 0.f, px = 0.f, py = 0.f, pz = 0.f;
        if (lane < KNN) {
            wgt = __expf((dmin - d2v) * invt2);
            const int idx = (int)(unsigned)(sel & 0xFFFFFFFFull);
            const float4 pp = p2[idx];
            px = pp.x; py = pp.y; pz = pp.z;
        }
        float sw = wgt, sx = wgt * px, sy = wgt * py, sz = wgt * pz;
        #pragma unroll
        for (int off = 8; off >= 1; off >>= 1) {
            sw += __shfl_xor(sw, off);
            sx += __shfl_xor(sx, off);
            sy += __shfl_xor(sy, off);
            sz += __shfl_xor(sz, off);
        }
        if (lane == 0) {
            const float inv = 1.0f / sw;
            out[(size_t)gid * 3 + 0] = sx * inv;
            out[(size_t)gid * 3 + 1] = sy * inv;
            out[(size_t)gid * 3 + 2] = sz * inv;
            if (gid == 0) out[NSMP * 3] = t;    // tuple output 2: temp
        }
    }
}

extern "C" void kernel_launch(void* const* d_in, const int* in_sizes, int n_in,
                              void* d_out, int out_size, void* d_ws, size_t ws_size,
                              hipStream_t stream) {
    const float* xyz  = (const float*)d_in[0];   // [8,16384,3]
    const float* sxyz = (const float*)d_in[1];   // [8,1024,3]
    const float* temp = (const float*)d_in[2];   // scalar
    float* out = (float*)d_out;

    float4* pk  = (float4*)d_ws;                              // 2 MiB plane-paired
    float4* pk2 = (float4*)((char*)d_ws + (size_t)131072*16); // 2 MiB linear

    hipLaunchKernelGGL(pack_kernel, dim3(256), dim3(256), 0, stream, xyz, pk, pk2);
    hipLaunchKernelGGL(knn_kernel, dim3(NSMP / QPB), dim3(256), 0, stream,
                       pk, pk2, sxyz, temp, out);
}